// Round 13
// baseline (340.328 us; speedup 1.0000x reference)
//
#include <hip/hip_runtime.h>
#include <stdint.h>

#define B_ 8
#define C_ 256
#define N_ 4096
#define CQK 32
#define VPANEL (C_ * 64)   // f16 elements per 64-key V panel (256 c x 64 j)
#define BPSTRIDE 520       // bp chunk stride in f16 (64*8 + 8 pad -> bank offset 4)

#define PSTRIDE 264        // P row stride bytes (256 data + 8 pad): 4-way max
#define PBUF    16896      // 64 * PSTRIDE
#define KSTRIDE 36         // K stage row stride f16 (32 data + 4 pad): <=2-way
#define KBUF    4608       // 128 * KSTRIDE

typedef __attribute__((ext_vector_type(8))) _Float16 f16x8;
typedef __attribute__((ext_vector_type(4))) float f32x4;

__device__ __forceinline__ unsigned short f2bf_rne(float f) {
  unsigned u = __builtin_bit_cast(unsigned, f);
  u += 0x7FFFu + ((u >> 16) & 1u);
  return (unsigned short)(u >> 16);
}

// raw v_exp_f32: 2^x in ONE instruction (libm exp2f adds a denorm-range
// fixup sequence). Valid here: x <= 8 always; deep-negative flushes to 0.
__device__ __forceinline__ float fexp2(float x) {
  float r; asm("v_exp_f32 %0, %1" : "=v"(r) : "v"(x)); return r;
}

// ---------------------------------------------------------------------------
// Kernel 2: convert weights to fp16, concatenated Wcat[320][256].
// Blocks 0-15 also zero the BN stats accumulator stats[8 b][2][256 c].
// ---------------------------------------------------------------------------
__global__ __launch_bounds__(256) void wconv_kernel(
    const float* __restrict__ wq, const float* __restrict__ wk,
    const float* __restrict__ wv, _Float16* __restrict__ wf,
    float* __restrict__ stats)
{
  int idx = blockIdx.x * 256 + threadIdx.x;   // 20480 threads x 4 elems
  if (idx < 4096) stats[idx] = 0.f;
  int e = idx * 4;
  int o = e >> 8, c = e & 255;
  const float* src;
  if (o < 32)      src = wq + o * 256 + c;
  else if (o < 64) src = wk + (o - 32) * 256 + c;
  else             src = wv + (o - 64) * 256 + c;
  float4 v = *(const float4*)src;
  _Float16 h[4] = {(_Float16)v.x, (_Float16)v.y, (_Float16)v.z, (_Float16)v.w};
  *(uint2*)(wf + e) = *(uint2*)h;
}

// ---------------------------------------------------------------------------
// FUSED projection (round-12, unchanged): x -> LDS transpose -> q/k/v MFMA.
// ---------------------------------------------------------------------------
__global__ __launch_bounds__(256, 2) void proj_fused_kernel(
    const float* __restrict__ x, const _Float16* __restrict__ wf,
    const float* __restrict__ bq, const float* __restrict__ bk,
    const float* __restrict__ bv,
    _Float16* __restrict__ qf, _Float16* __restrict__ kf,
    _Float16* __restrict__ vout)
{
  __shared__ float xs[2][64 * 65];           // fp32 stage: DOUBLE-buffered
  __shared__ _Float16 bp[32 * BPSTRIDE];     // packed B: [c/8 chunk][n][8c] f16

  const int t = threadIdx.x, lane = t & 63;
  const int w = t >> 6;
  const int l15 = lane & 15, q4 = lane >> 4;
  const int blk = blockIdx.x;
  const int b  = blk & 7;                  // batch == XCD (matches attn)
  const int nt = blk >> 3;                 // 64 n-tiles of 64 px
  const int n0 = nt * 64;
  const int o0w = (w & 1) * 32;            // wave o-offset within 64-row otile
  const int n0w = (w >> 1) * 32;           // wave n-offset within 64-px tile

  const int cc = (t >> 4);                 // this thread's c-row within 16-group
  const int nn = (t & 15) * 4;             // this thread's n-quad

  // ---- prologue: chunk 0 -> xs[0] ----
  {
    float4 v0[4];
    #pragma unroll
    for (int p = 0; p < 4; ++p)
      v0[p] = *(const float4*)(x + ((size_t)(b * C_) + p * 16 + cc) * N_ + n0 + nn);
    #pragma unroll
    for (int p = 0; p < 4; ++p) {
      float* dst = &xs[0][(p * 16 + cc) * 65 + nn];
      dst[0] = v0[p].x; dst[1] = v0[p].y; dst[2] = v0[p].z; dst[3] = v0[p].w;
    }
  }
  __syncthreads();

  // ---- pipelined staging: transpose ct while loading ct+1 ----
  for (int ct = 0; ct < 4; ++ct) {
    float4 vn[4];
    if (ct < 3) {
      #pragma unroll
      for (int p = 0; p < 4; ++p)
        vn[p] = *(const float4*)(x + ((size_t)(b * C_) + (ct + 1) * 64 + p * 16 + cc) * N_ + n0 + nn);
    }
    #pragma unroll
    for (int h = 0; h < 2; ++h) {
      int oct = w + h * 4;                 // 0..7 (c-octet within chunk)
      int n = lane;                        // 0..63
      _Float16 hh[8];
      #pragma unroll
      for (int j = 0; j < 8; ++j) hh[j] = (_Float16)xs[ct & 1][(oct * 8 + j) * 65 + n];
      *(f16x8*)(bp + (size_t)(ct * 8 + oct) * BPSTRIDE + n * 8) = *(f16x8*)hh;
    }
    if (ct < 3) {
      #pragma unroll
      for (int p = 0; p < 4; ++p) {
        float* dst = &xs[(ct + 1) & 1][(p * 16 + cc) * 65 + nn];
        dst[0] = vn[p].x; dst[1] = vn[p].y; dst[2] = vn[p].z; dst[3] = vn[p].w;
      }
      __syncthreads();   // writes to xs[(ct+1)&1] visible; xs[ct&1] reads done
    }
  }
  __syncthreads();       // bp complete before compute

  // ---- compute all 5 otiles from the staged tile ----
  const f32x4 zf = {0.f, 0.f, 0.f, 0.f};
  for (int otile = 0; otile < 5; ++otile) {
    f32x4 acc[2][2];
    #pragma unroll
    for (int a = 0; a < 2; ++a)
      #pragma unroll
      for (int bb = 0; bb < 2; ++bb) acc[a][bb] = zf;

    const _Float16* wbase = wf + (size_t)(otile * 64 + o0w) * 256;

    #pragma unroll 2
    for (int kc = 0; kc < 8; ++kc) {
      f16x8 af[2], bfr[2];
      #pragma unroll
      for (int ob = 0; ob < 2; ++ob)
        af[ob] = *(const f16x8*)(wbase + (ob * 16 + l15) * 256 + kc * 32 + q4 * 8);
      #pragma unroll
      for (int nb = 0; nb < 2; ++nb)
        bfr[nb] = *(const f16x8*)(bp + (size_t)(kc * 4 + q4) * BPSTRIDE + (n0w + nb * 16 + l15) * 8);
      #pragma unroll
      for (int ob = 0; ob < 2; ++ob)
        #pragma unroll
        for (int nb = 0; nb < 2; ++nb)
          acc[ob][nb] = __builtin_amdgcn_mfma_f32_16x16x32_f16(af[ob], bfr[nb], acc[ob][nb], 0, 0, 0);
    }

    if (otile == 0) {
      _Float16* dst = (o0w == 0) ? qf : kf;
      const float* bias = (o0w == 0) ? bq : bk;
      const float qsc = (o0w == 0) ? 1.4426950408889634f : 1.0f;  // log2(e) for q
      #pragma unroll
      for (int ob = 0; ob < 2; ++ob) {
        float4 b4 = *(const float4*)(bias + ob * 16 + q4 * 4);
        #pragma unroll
        for (int nb = 0; nb < 2; ++nb) {
          int pixel = n0 + n0w + nb * 16 + l15;
          _Float16 h[4];
          h[0] = (_Float16)((acc[ob][nb][0] + b4.x) * qsc);
          h[1] = (_Float16)((acc[ob][nb][1] + b4.y) * qsc);
          h[2] = (_Float16)((acc[ob][nb][2] + b4.z) * qsc);
          h[3] = (_Float16)((acc[ob][nb][3] + b4.w) * qsc);
          *(uint2*)(dst + ((size_t)(b * N_) + pixel) * CQK + ob * 16 + q4 * 4) = *(uint2*)h;
        }
      }
    } else {
      int cbase = (otile - 1) * 64 + o0w;
      _Float16* vpan = vout + ((size_t)(b * 64 + nt)) * VPANEL;
      #pragma unroll
      for (int ob = 0; ob < 2; ++ob) {
        float4 b4 = *(const float4*)(bv + cbase + ob * 16 + q4 * 4);
        #pragma unroll
        for (int nb = 0; nb < 2; ++nb) {
          int jj = n0w + nb * 16 + l15;        // j within panel, 0..63
          #pragma unroll
          for (int r = 0; r < 4; ++r) {
            int c = cbase + ob * 16 + q4 * 4 + r;
            float bval = (r == 0) ? b4.x : (r == 1) ? b4.y : (r == 2) ? b4.z : b4.w;
            vpan[(size_t)c * 64 + jj] = (_Float16)(acc[ob][nb][r] + bval);
          }
        }
      }
    }
  }
}

// ---------------------------------------------------------------------------
// Kernel 4: fused flash attention + residual -> yout (bf16) + BN STATS.
// ROUND-13: LDS shaved 56096 -> 53024 B so THREE blocks fit per CU
// (163840/3 = 54613): 8 -> 12 waves/CU, letting one block's S-phase
// (VALU/MFMA) overlap another's PV (DS-heavy). Stride changes double as
// bank fixes: P row 272->264 B turns the P-read 8-way conflict (start bank
// 4*(l15+q4)) into <=4-way (2*l15+4*q4); K stage row 40->36 f16 stays
// <=2-way. Schedule/numerics byte-identical otherwise.
// ---------------------------------------------------------------------------
#define ATTN_BODY(K, BUF) do { \
  /* staging regs for K(K+1): global loads issued FIRST, ds_write LAST */ \
  f16x8 ks_[2]; \
  { const _Float16* kg_ = kstage + (size_t)(((K) + 1) & 31) * (128 * CQK); \
    _Pragma("unroll") \
    for (int s = 0; s < 2; ++s) { \
      int idx_ = s * 256 + t; \
      ks_[s] = *(const f16x8*)(kg_ + (idx_ >> 2) * CQK + (idx_ & 3) * 8); } } \
  /* V(K) loads -- consumed after the barrier in PV */ \
  f16x8 vx_[16]; \
  { const _Float16* vp_ = vbase + (size_t)(K) * 2 * VPANEL; \
    _Pragma("unroll") \
    for (int ks = 0; ks < 4; ++ks) \
      _Pragma("unroll") \
      for (int cb = 0; cb < 4; ++cb) \
        vx_[ks * 4 + cb] = *(const f16x8*)(vp_ + (ks >> 1) * VPANEL + cb * 1024 + (ks & 1) * 32); } \
  /* K(K) frags from LDS buf K&1 */ \
  f16x8 kx_[8]; \
  { const _Float16* kl_ = Klds + ((K) & 1) * KBUF + l15 * KSTRIDE + q4 * 8; \
    _Pragma("unroll") \
    for (int jb = 0; jb < 8; ++jb) kx_[jb] = *(const f16x8*)(kl_ + jb * (16 * KSTRIDE)); } \
  f32x4 sv_[8]; \
  _Pragma("unroll") \
  for (int jb = 0; jb < 8; ++jb) \
    sv_[jb] = __builtin_amdgcn_mfma_f32_16x16x32_f16(kx_[jb], qfr, zf, 0, 0, 0); \
  float pm_[8]; \
  _Pragma("unroll") \
  for (int jb = 0; jb < 8; ++jb) \
    pm_[jb] = fmaxf(fmaxf(sv_[jb][0], sv_[jb][1]), fmaxf(sv_[jb][2], sv_[jb][3])); \
  float ra_ = fmaxf(fmaxf(pm_[0], pm_[1]), pm_[2]); \
  float rb_ = fmaxf(fmaxf(pm_[3], pm_[4]), pm_[5]); \
  float rc_ = fmaxf(fmaxf(pm_[6], pm_[7]), ra_); \
  float lm_ = fmaxf(rb_, rc_); \
  lm_ = fmaxf(lm_, __shfl_xor(lm_, 16)); \
  lm_ = fmaxf(lm_, __shfl_xor(lm_, 32)); \
  bool upd_ = lm_ > mold + 8.0f; \
  unsigned long long bal_ = __ballot(upd_);     /* full-wave scope */ \
  float alpha_ = upd_ ? fexp2(mold - lm_) : 1.0f; \
  if (upd_) mold = lm_; \
  float ts_ = 0.f; \
  { char* pb_ = (char*)Plds + (BUF) * PBUF + (w * 16 + l15) * PSTRIDE + q4 * 8; \
    _Pragma("unroll") \
    for (int jb = 0; jb < 8; ++jb) { \
      float p0_ = fexp2(sv_[jb][0] - mold), p1_ = fexp2(sv_[jb][1] - mold); \
      float p2_ = fexp2(sv_[jb][2] - mold), p3_ = fexp2(sv_[jb][3] - mold); \
      ts_ += (p0_ + p1_) + (p2_ + p3_); \
      _Float16 h_[4] = {(_Float16)p0_, (_Float16)p1_, (_Float16)p2_, (_Float16)p3_}; \
      *(uint2*)(pb_ + jb * 32) = *(uint2*)h_; } } \
  /* write staged K(K+1) into buf (K+1)&1 (pre-barrier) */ \
  { _Float16* kw_ = Klds + (((K) + 1) & 1) * KBUF; \
    _Pragma("unroll") \
    for (int s = 0; s < 2; ++s) { \
      int idx_ = s * 256 + t; \
      *(f16x8*)(kw_ + (idx_ >> 2) * KSTRIDE + (idx_ & 3) * 8) = ks_[s]; } } \
  if (q4 == 0) alphal[(BUF) * 64 + w * 16 + l15] = alpha_; \
  if (lane == 0) flagw[(BUF) * 4 + w] = (bal_ != 0ull) ? 1 : 0; \
  ts_ += __shfl_xor(ts_, 16); \
  ts_ += __shfl_xor(ts_, 32); \
  lrun = lrun * alpha_ + ts_; \
  asm volatile("s_waitcnt lgkmcnt(0)" ::: "memory"); \
  __builtin_amdgcn_sched_barrier(0); \
  __builtin_amdgcn_s_barrier(); \
  asm volatile("" ::: "memory"); \
  { int4 fl_ = *(const int4*)(flagw + (BUF) * 4); \
    if (fl_.x | fl_.y | fl_.z | fl_.w) { \
      _Pragma("unroll") \
      for (int ib = 0; ib < 4; ++ib) { \
        float av_ = alphal[(BUF) * 64 + ib * 16 + l15]; \
        _Pragma("unroll") \
        for (int cb = 0; cb < 4; ++cb) \
          _Pragma("unroll") \
          for (int r = 0; r < 4; ++r) acc[cb][ib][r] *= av_; } } } \
  __builtin_amdgcn_s_setprio(1); \
  _Pragma("unroll") \
  for (int ks = 0; ks < 4; ++ks) { \
    f16x8 pf_[4]; \
    _Pragma("unroll") \
    for (int ib = 0; ib < 4; ++ib) \
      pf_[ib] = *(const f16x8*)((char*)Plds + (BUF) * PBUF + (ib * 16 + l15) * PSTRIDE + ks * 64 + q4 * 16); \
    _Pragma("unroll") \
    for (int cb = 0; cb < 4; ++cb) \
      _Pragma("unroll") \
      for (int ib = 0; ib < 4; ++ib) \
        acc[cb][ib] = __builtin_amdgcn_mfma_f32_16x16x32_f16(vx_[ks * 4 + cb], pf_[ib], acc[cb][ib], 0, 0, 0); \
  } \
  __builtin_amdgcn_s_setprio(0); \
} while (0)

__global__ __launch_bounds__(256, 2) void attn_kernel(
    const float* __restrict__ x, const float* __restrict__ gptr,
    const _Float16* __restrict__ qf, const _Float16* __restrict__ kf,
    const _Float16* __restrict__ vf, unsigned short* __restrict__ yout,
    float* __restrict__ stats)
{
  __shared__ __align__(16) char smem[53024];
  _Float16* Plds  = (_Float16*)smem;             // [2][64 rows][264 B] = 33792
  _Float16* Klds  = (_Float16*)(smem + 33792);   // [2][128 rows][36 f16] = 18432
  float* alphal = (float*)(smem + 52224);        // [2][64]
  int*   flagw  = (int*)(smem + 52736);          // [2][4]
  float* lrowl  = (float*)(smem + 52768);        // [64]

  const int t = threadIdx.x, lane = t & 63;
  const int w = t >> 6;                           // 4 waves
  const int l15 = lane & 15, q4 = lane >> 4;
  const int b  = blockIdx.x & 7;                  // batch == XCD
  const int it = blockIdx.x >> 3;
  const int i0 = it * 64;
  const float gamma = gptr[0];

  const f16x8 qfr = *(const f16x8*)(qf + ((size_t)(b * N_) + i0 + w * 16 + l15) * CQK + q4 * 8);

  // block-level K base (cooperative LDS staging)
  const _Float16* kstage = kf + (size_t)b * N_ * CQK;
  // per-lane V base (panel-major): c-row = w*64 (+cb*16) + l15, j-chunk q4*8
  const _Float16* vbase = vf + (size_t)b * (64 * VPANEL)
                             + ((size_t)(w * 64 + l15)) * 64 + q4 * 8;

  f32x4 acc[4][4];   // [cb][ib]: c = w*64+cb*16+q4*4+r, i = ib*16+l15
  const f32x4 zf = {0.f, 0.f, 0.f, 0.f};
  #pragma unroll
  for (int a = 0; a < 4; ++a)
    #pragma unroll
    for (int bb = 0; bb < 4; ++bb) acc[a][bb] = zf;

  float mold = -1e30f, lrun = 0.f;

  // prologue: stage K(0) into buf 0
  #pragma unroll
  for (int s = 0; s < 2; ++s) {
    int idx = s * 256 + t;
    f16x8 v = *(const f16x8*)(kstage + (idx >> 2) * CQK + (idx & 3) * 8);
    *(f16x8*)(Klds + (idx >> 2) * KSTRIDE + (idx & 3) * 8) = v;
  }
  __syncthreads();

  #pragma unroll 1
  for (int k = 0; k < 32; k += 2) {
    ATTN_BODY(k, 0);
    ATTN_BODY(k + 1, 1);
  }

  if (q4 == 0) lrowl[w * 16 + l15] = lrun;
  __syncthreads();
  float linv[4];
  #pragma unroll
  for (int ib = 0; ib < 4; ++ib) linv[ib] = 1.0f / lrowl[ib * 16 + l15];

  // epilogue: residual + yout store + fused BN stats into the PER-BATCH
  // stats copy (stats + b*512): 64 same-address atomics instead of 512.
  float* sb = stats + b * 512;
  #pragma unroll
  for (int cb = 0; cb < 4; ++cb) {
    #pragma unroll
    for (int r = 0; r < 4; ++r) {
      int c = w * 64 + cb * 16 + q4 * 4 + r;
      float s1 = 0.f, s2 = 0.f;
      #pragma unroll
      for (int ib = 0; ib < 4; ++ib) {
        int i = i0 + ib * 16 + l15;
        size_t off = ((size_t)(b * C_) + c) * N_ + i;
        float y = fmaf(gamma, acc[cb][ib][r] * linv[ib], x[off]);
        yout[off] = f2bf_rne(y);
        s1 += y;
        s2 += y * y;
      }
      #pragma unroll
      for (int m = 1; m < 16; m <<= 1) {
        s1 += __shfl_xor(s1, m);
        s2 += __shfl_xor(s2, m);
      }
      if (l15 == 0) {
        atomicAdd(sb + c, s1);
        atomicAdd(sb + 256 + c, s2);
      }
    }
  }
}

// ---------------------------------------------------------------------------
// Kernel 6: BN normalize + ReLU: bf16 yout -> fp32 d_out.
// mean/rstd from the 8 per-batch stats copies.
// ---------------------------------------------------------------------------
__global__ __launch_bounds__(256) void bnapply_kernel(
    const unsigned short* __restrict__ y, float* __restrict__ out,
    const float* __restrict__ stats,
    const float* __restrict__ bnw, const float* __restrict__ bnb)
{
  size_t idx = (size_t)blockIdx.x * 256 + threadIdx.x;   // 1,048,576 threads
  size_t el = idx * 8;
  int c = (int)((el >> 12) & 255);
  float s1 = 0.f, s2 = 0.f;
  #pragma unroll
  for (int bb = 0; bb < 8; ++bb) {
    s1 += stats[bb * 512 + c];
    s2 += stats[bb * 512 + 256 + c];
  }
  float mean = s1 * (1.0f / 32768.0f);
  float var  = fmaf(-mean, mean, s2 * (1.0f / 32768.0f));
  float rstd = rsqrtf(var + 1e-5f);
  float sc = bnw[c] * rstd;
  float sh = fmaf(-mean, sc, bnb[c]);
  uint4 u = *(const uint4*)(y + el);
  unsigned uu[4] = {u.x, u.y, u.z, u.w};
  float4 o0, o1;
  float v[8];
  #pragma unroll
  for (int k = 0; k < 4; ++k) {
    v[2 * k]     = __builtin_bit_cast(float, uu[k] << 16);
    v[2 * k + 1] = __builtin_bit_cast(float, uu[k] & 0xFFFF0000u);
  }
  o0.x = fmaxf(fmaf(v[0], sc, sh), 0.f);
  o0.y = fmaxf(fmaf(v[1], sc, sh), 0.f);
  o0.z = fmaxf(fmaf(v[2], sc, sh), 0.f);
  o0.w = fmaxf(fmaf(v[3], sc, sh), 0.f);
  o1.x = fmaxf(fmaf(v[4], sc, sh), 0.f);
  o1.y = fmaxf(fmaf(v[5], sc, sh), 0.f);
  o1.z = fmaxf(fmaf(v[6], sc, sh), 0.f);
  o1.w = fmaxf(fmaf(v[7], sc, sh), 0.f);
  *(float4*)(out + el) = o0;
  *(float4*)(out + el + 4) = o1;
}

extern "C" void kernel_launch(void* const* d_in, const int* in_sizes, int n_in,
                              void* d_out, int out_size, void* d_ws, size_t ws_size,
                              hipStream_t stream)
{
  const float* x   = (const float*)d_in[0];
  const float* wq  = (const float*)d_in[1];
  const float* bq  = (const float*)d_in[2];
  const float* wk  = (const float*)d_in[3];
  const float* bk  = (const float*)d_in[4];
  const float* wv  = (const float*)d_in[5];
  const float* bv  = (const float*)d_in[6];
  const float* gm  = (const float*)d_in[7];
  const float* bnw = (const float*)d_in[8];
  const float* bnb = (const float*)d_in[9];
  float* out = (float*)d_out;

  // d_out doubles as scratch for v (dead before bnapply writes):
  //   [16.78, 33.55)  v fp16 PANEL-MAJOR [b][64 jt][256 c][64 j]
  _Float16* vfp = (_Float16*)((char*)d_out + (size_t)B_ * C_ * N_ * 2);

  // ws: q 2MB | k 2MB | yout bf16 16.78MB | wf 160KB | stats[8][512]
  char* ws = (char*)d_ws;
  _Float16* qf = (_Float16*)(ws);
  _Float16* kf = (_Float16*)(ws + ((size_t)2 << 20));
  unsigned short* yout = (unsigned short*)(ws + ((size_t)4 << 20));
  _Float16* wf = (_Float16*)(ws + ((size_t)21 << 20));
  float* stats = (float*)(ws + ((size_t)22 << 20));

  hipLaunchKernelGGL(wconv_kernel, dim3(80), dim3(256), 0, stream,
                     wq, wk, wv, wf, stats);
  hipLaunchKernelGGL(proj_fused_kernel, dim3(512), dim3(256), 0, stream,
                     x, wf, bq, bk, bv, qf, kf, vfp);
  hipLaunchKernelGGL(attn_kernel, dim3(512), dim3(256), 0, stream,
                     x, gm, qf, kf, vfp, yout, stats);
  hipLaunchKernelGGL(bnapply_kernel, dim3(4096), dim3(256), 0, stream,
                     yout, out, stats, bnw, bnb);
}

// Round 14
// 259.949 us; speedup vs baseline: 1.3092x; 1.3092x over previous
//
#include <hip/hip_runtime.h>
#include <stdint.h>

#define B_ 8
#define C_ 256
#define N_ 4096
#define CQK 32
#define VPANEL (C_ * 64)   // f16 elements per 64-key V panel (256 c x 64 j)
#define BPSTRIDE 520       // bp chunk stride in f16 (64*8 + 8 pad -> bank offset 4)

// LDS strides for f16x8 (16B) ops MUST be multiples of 16B: round-13's
// 264/72B strides broke static alignment -> compiler split b128 into
// b64/b32 (bank-conflict counter -> 0, DS issue 2-4x, attn 148->229us).
#define PSTRIDE 272        // P row stride bytes (16B-aligned; 8-group b128 spread = minimum aliasing)
#define PBUF    17408      // 64 * PSTRIDE
#define KSTRIDE 40         // K stage row stride f16 (80B, 16B-aligned)
#define KBUF    5120       // 128 * KSTRIDE

typedef __attribute__((ext_vector_type(8))) _Float16 f16x8;
typedef __attribute__((ext_vector_type(4))) float f32x4;

__device__ __forceinline__ unsigned short f2bf_rne(float f) {
  unsigned u = __builtin_bit_cast(unsigned, f);
  u += 0x7FFFu + ((u >> 16) & 1u);
  return (unsigned short)(u >> 16);
}

// raw v_exp_f32: 2^x in ONE instruction (libm exp2f adds a denorm-range
// fixup sequence). Valid here: x <= 8 always; deep-negative flushes to 0.
__device__ __forceinline__ float fexp2(float x) {
  float r; asm("v_exp_f32 %0, %1" : "=v"(r) : "v"(x)); return r;
}

// ---------------------------------------------------------------------------
// Kernel 2: convert weights to fp16, concatenated Wcat[320][256].
// Blocks 0-15 also zero the BN stats accumulator stats[8 b][2][256 c].
// ---------------------------------------------------------------------------
__global__ __launch_bounds__(256) void wconv_kernel(
    const float* __restrict__ wq, const float* __restrict__ wk,
    const float* __restrict__ wv, _Float16* __restrict__ wf,
    float* __restrict__ stats)
{
  int idx = blockIdx.x * 256 + threadIdx.x;   // 20480 threads x 4 elems
  if (idx < 4096) stats[idx] = 0.f;
  int e = idx * 4;
  int o = e >> 8, c = e & 255;
  const float* src;
  if (o < 32)      src = wq + o * 256 + c;
  else if (o < 64) src = wk + (o - 32) * 256 + c;
  else             src = wv + (o - 64) * 256 + c;
  float4 v = *(const float4*)src;
  _Float16 h[4] = {(_Float16)v.x, (_Float16)v.y, (_Float16)v.z, (_Float16)v.w};
  *(uint2*)(wf + e) = *(uint2*)h;
}

// ---------------------------------------------------------------------------
// FUSED projection (round-12, unchanged): x -> LDS transpose -> q/k/v MFMA.
// ---------------------------------------------------------------------------
__global__ __launch_bounds__(256, 2) void proj_fused_kernel(
    const float* __restrict__ x, const _Float16* __restrict__ wf,
    const float* __restrict__ bq, const float* __restrict__ bk,
    const float* __restrict__ bv,
    _Float16* __restrict__ qf, _Float16* __restrict__ kf,
    _Float16* __restrict__ vout)
{
  __shared__ float xs[2][64 * 65];           // fp32 stage: DOUBLE-buffered
  __shared__ _Float16 bp[32 * BPSTRIDE];     // packed B: [c/8 chunk][n][8c] f16

  const int t = threadIdx.x, lane = t & 63;
  const int w = t >> 6;
  const int l15 = lane & 15, q4 = lane >> 4;
  const int blk = blockIdx.x;
  const int b  = blk & 7;                  // batch == XCD (matches attn)
  const int nt = blk >> 3;                 // 64 n-tiles of 64 px
  const int n0 = nt * 64;
  const int o0w = (w & 1) * 32;            // wave o-offset within 64-row otile
  const int n0w = (w >> 1) * 32;           // wave n-offset within 64-px tile

  const int cc = (t >> 4);                 // this thread's c-row within 16-group
  const int nn = (t & 15) * 4;             // this thread's n-quad

  // ---- prologue: chunk 0 -> xs[0] ----
  {
    float4 v0[4];
    #pragma unroll
    for (int p = 0; p < 4; ++p)
      v0[p] = *(const float4*)(x + ((size_t)(b * C_) + p * 16 + cc) * N_ + n0 + nn);
    #pragma unroll
    for (int p = 0; p < 4; ++p) {
      float* dst = &xs[0][(p * 16 + cc) * 65 + nn];
      dst[0] = v0[p].x; dst[1] = v0[p].y; dst[2] = v0[p].z; dst[3] = v0[p].w;
    }
  }
  __syncthreads();

  // ---- pipelined staging: transpose ct while loading ct+1 ----
  for (int ct = 0; ct < 4; ++ct) {
    float4 vn[4];
    if (ct < 3) {
      #pragma unroll
      for (int p = 0; p < 4; ++p)
        vn[p] = *(const float4*)(x + ((size_t)(b * C_) + (ct + 1) * 64 + p * 16 + cc) * N_ + n0 + nn);
    }
    #pragma unroll
    for (int h = 0; h < 2; ++h) {
      int oct = w + h * 4;                 // 0..7 (c-octet within chunk)
      int n = lane;                        // 0..63
      _Float16 hh[8];
      #pragma unroll
      for (int j = 0; j < 8; ++j) hh[j] = (_Float16)xs[ct & 1][(oct * 8 + j) * 65 + n];
      *(f16x8*)(bp + (size_t)(ct * 8 + oct) * BPSTRIDE + n * 8) = *(f16x8*)hh;
    }
    if (ct < 3) {
      #pragma unroll
      for (int p = 0; p < 4; ++p) {
        float* dst = &xs[(ct + 1) & 1][(p * 16 + cc) * 65 + nn];
        dst[0] = vn[p].x; dst[1] = vn[p].y; dst[2] = vn[p].z; dst[3] = vn[p].w;
      }
      __syncthreads();   // writes to xs[(ct+1)&1] visible; xs[ct&1] reads done
    }
  }
  __syncthreads();       // bp complete before compute

  // ---- compute all 5 otiles from the staged tile ----
  const f32x4 zf = {0.f, 0.f, 0.f, 0.f};
  for (int otile = 0; otile < 5; ++otile) {
    f32x4 acc[2][2];
    #pragma unroll
    for (int a = 0; a < 2; ++a)
      #pragma unroll
      for (int bb = 0; bb < 2; ++bb) acc[a][bb] = zf;

    const _Float16* wbase = wf + (size_t)(otile * 64 + o0w) * 256;

    #pragma unroll 2
    for (int kc = 0; kc < 8; ++kc) {
      f16x8 af[2], bfr[2];
      #pragma unroll
      for (int ob = 0; ob < 2; ++ob)
        af[ob] = *(const f16x8*)(wbase + (ob * 16 + l15) * 256 + kc * 32 + q4 * 8);
      #pragma unroll
      for (int nb = 0; nb < 2; ++nb)
        bfr[nb] = *(const f16x8*)(bp + (size_t)(kc * 4 + q4) * BPSTRIDE + (n0w + nb * 16 + l15) * 8);
      #pragma unroll
      for (int ob = 0; ob < 2; ++ob)
        #pragma unroll
        for (int nb = 0; nb < 2; ++nb)
          acc[ob][nb] = __builtin_amdgcn_mfma_f32_16x16x32_f16(af[ob], bfr[nb], acc[ob][nb], 0, 0, 0);
    }

    if (otile == 0) {
      _Float16* dst = (o0w == 0) ? qf : kf;
      const float* bias = (o0w == 0) ? bq : bk;
      const float qsc = (o0w == 0) ? 1.4426950408889634f : 1.0f;  // log2(e) for q
      #pragma unroll
      for (int ob = 0; ob < 2; ++ob) {
        float4 b4 = *(const float4*)(bias + ob * 16 + q4 * 4);
        #pragma unroll
        for (int nb = 0; nb < 2; ++nb) {
          int pixel = n0 + n0w + nb * 16 + l15;
          _Float16 h[4];
          h[0] = (_Float16)((acc[ob][nb][0] + b4.x) * qsc);
          h[1] = (_Float16)((acc[ob][nb][1] + b4.y) * qsc);
          h[2] = (_Float16)((acc[ob][nb][2] + b4.z) * qsc);
          h[3] = (_Float16)((acc[ob][nb][3] + b4.w) * qsc);
          *(uint2*)(dst + ((size_t)(b * N_) + pixel) * CQK + ob * 16 + q4 * 4) = *(uint2*)h;
        }
      }
    } else {
      int cbase = (otile - 1) * 64 + o0w;
      _Float16* vpan = vout + ((size_t)(b * 64 + nt)) * VPANEL;
      #pragma unroll
      for (int ob = 0; ob < 2; ++ob) {
        float4 b4 = *(const float4*)(bv + cbase + ob * 16 + q4 * 4);
        #pragma unroll
        for (int nb = 0; nb < 2; ++nb) {
          int jj = n0w + nb * 16 + l15;        // j within panel, 0..63
          #pragma unroll
          for (int r = 0; r < 4; ++r) {
            int c = cbase + ob * 16 + q4 * 4 + r;
            float bval = (r == 0) ? b4.x : (r == 1) ? b4.y : (r == 2) ? b4.z : b4.w;
            vpan[(size_t)c * 64 + jj] = (_Float16)(acc[ob][nb][r] + bval);
          }
        }
      }
    }
  }
}

// ---------------------------------------------------------------------------
// Kernel 4: fused flash attention + residual -> yout (bf16) + BN STATS.
// BYTE-IDENTICAL loop to rounds 10-12 (148us): NT=128, 32 bodies, 4 waves,
// LDS-staged K (16B-aligned strides!), raw v_exp, 1 lgkm-only barrier/body,
// per-batch spread stats atomics in the epilogue.
// ---------------------------------------------------------------------------
#define ATTN_BODY(K, BUF) do { \
  /* staging regs for K(K+1): global loads issued FIRST, ds_write LAST */ \
  f16x8 ks_[2]; \
  { const _Float16* kg_ = kstage + (size_t)(((K) + 1) & 31) * (128 * CQK); \
    _Pragma("unroll") \
    for (int s = 0; s < 2; ++s) { \
      int idx_ = s * 256 + t; \
      ks_[s] = *(const f16x8*)(kg_ + (idx_ >> 2) * CQK + (idx_ & 3) * 8); } } \
  /* V(K) loads -- consumed after the barrier in PV */ \
  f16x8 vx_[16]; \
  { const _Float16* vp_ = vbase + (size_t)(K) * 2 * VPANEL; \
    _Pragma("unroll") \
    for (int ks = 0; ks < 4; ++ks) \
      _Pragma("unroll") \
      for (int cb = 0; cb < 4; ++cb) \
        vx_[ks * 4 + cb] = *(const f16x8*)(vp_ + (ks >> 1) * VPANEL + cb * 1024 + (ks & 1) * 32); } \
  /* K(K) frags from LDS buf K&1 */ \
  f16x8 kx_[8]; \
  { const _Float16* kl_ = Klds + ((K) & 1) * KBUF + l15 * KSTRIDE + q4 * 8; \
    _Pragma("unroll") \
    for (int jb = 0; jb < 8; ++jb) kx_[jb] = *(const f16x8*)(kl_ + jb * (16 * KSTRIDE)); } \
  f32x4 sv_[8]; \
  _Pragma("unroll") \
  for (int jb = 0; jb < 8; ++jb) \
    sv_[jb] = __builtin_amdgcn_mfma_f32_16x16x32_f16(kx_[jb], qfr, zf, 0, 0, 0); \
  float pm_[8]; \
  _Pragma("unroll") \
  for (int jb = 0; jb < 8; ++jb) \
    pm_[jb] = fmaxf(fmaxf(sv_[jb][0], sv_[jb][1]), fmaxf(sv_[jb][2], sv_[jb][3])); \
  float ra_ = fmaxf(fmaxf(pm_[0], pm_[1]), pm_[2]); \
  float rb_ = fmaxf(fmaxf(pm_[3], pm_[4]), pm_[5]); \
  float rc_ = fmaxf(fmaxf(pm_[6], pm_[7]), ra_); \
  float lm_ = fmaxf(rb_, rc_); \
  lm_ = fmaxf(lm_, __shfl_xor(lm_, 16)); \
  lm_ = fmaxf(lm_, __shfl_xor(lm_, 32)); \
  bool upd_ = lm_ > mold + 8.0f; \
  unsigned long long bal_ = __ballot(upd_);     /* full-wave scope */ \
  float alpha_ = upd_ ? fexp2(mold - lm_) : 1.0f; \
  if (upd_) mold = lm_; \
  float ts_ = 0.f; \
  { char* pb_ = (char*)Plds + (BUF) * PBUF + (w * 16 + l15) * PSTRIDE + q4 * 8; \
    _Pragma("unroll") \
    for (int jb = 0; jb < 8; ++jb) { \
      float p0_ = fexp2(sv_[jb][0] - mold), p1_ = fexp2(sv_[jb][1] - mold); \
      float p2_ = fexp2(sv_[jb][2] - mold), p3_ = fexp2(sv_[jb][3] - mold); \
      ts_ += (p0_ + p1_) + (p2_ + p3_); \
      _Float16 h_[4] = {(_Float16)p0_, (_Float16)p1_, (_Float16)p2_, (_Float16)p3_}; \
      *(uint2*)(pb_ + jb * 32) = *(uint2*)h_; } } \
  /* write staged K(K+1) into buf (K+1)&1 (pre-barrier) */ \
  { _Float16* kw_ = Klds + (((K) + 1) & 1) * KBUF; \
    _Pragma("unroll") \
    for (int s = 0; s < 2; ++s) { \
      int idx_ = s * 256 + t; \
      *(f16x8*)(kw_ + (idx_ >> 2) * KSTRIDE + (idx_ & 3) * 8) = ks_[s]; } } \
  if (q4 == 0) alphal[(BUF) * 64 + w * 16 + l15] = alpha_; \
  if (lane == 0) flagw[(BUF) * 4 + w] = (bal_ != 0ull) ? 1 : 0; \
  ts_ += __shfl_xor(ts_, 16); \
  ts_ += __shfl_xor(ts_, 32); \
  lrun = lrun * alpha_ + ts_; \
  asm volatile("s_waitcnt lgkmcnt(0)" ::: "memory"); \
  __builtin_amdgcn_sched_barrier(0); \
  __builtin_amdgcn_s_barrier(); \
  asm volatile("" ::: "memory"); \
  { int4 fl_ = *(const int4*)(flagw + (BUF) * 4); \
    if (fl_.x | fl_.y | fl_.z | fl_.w) { \
      _Pragma("unroll") \
      for (int ib = 0; ib < 4; ++ib) { \
        float av_ = alphal[(BUF) * 64 + ib * 16 + l15]; \
        _Pragma("unroll") \
        for (int cb = 0; cb < 4; ++cb) \
          _Pragma("unroll") \
          for (int r = 0; r < 4; ++r) acc[cb][ib][r] *= av_; } } } \
  __builtin_amdgcn_s_setprio(1); \
  _Pragma("unroll") \
  for (int ks = 0; ks < 4; ++ks) { \
    f16x8 pf_[4]; \
    _Pragma("unroll") \
    for (int ib = 0; ib < 4; ++ib) \
      pf_[ib] = *(const f16x8*)((char*)Plds + (BUF) * PBUF + (ib * 16 + l15) * PSTRIDE + ks * 64 + q4 * 16); \
    _Pragma("unroll") \
    for (int cb = 0; cb < 4; ++cb) \
      _Pragma("unroll") \
      for (int ib = 0; ib < 4; ++ib) \
        acc[cb][ib] = __builtin_amdgcn_mfma_f32_16x16x32_f16(vx_[ks * 4 + cb], pf_[ib], acc[cb][ib], 0, 0, 0); \
  } \
  __builtin_amdgcn_s_setprio(0); \
} while (0)

__global__ __launch_bounds__(256, 2) void attn_kernel(
    const float* __restrict__ x, const float* __restrict__ gptr,
    const _Float16* __restrict__ qf, const _Float16* __restrict__ kf,
    const _Float16* __restrict__ vf, unsigned short* __restrict__ yout,
    float* __restrict__ stats)
{
  __shared__ __align__(16) char smem[56096];
  _Float16* Plds  = (_Float16*)smem;             // [2][64 rows][272 B]
  _Float16* Klds  = (_Float16*)(smem + 34816);   // [2][128 rows][40 f16 = 80 B]
  float* alphal = (float*)(smem + 55296);        // [2][64]
  int*   flagw  = (int*)(smem + 55808);          // [2][4]
  float* lrowl  = (float*)(smem + 55840);        // [64]

  const int t = threadIdx.x, lane = t & 63;
  const int w = t >> 6;                           // 4 waves
  const int l15 = lane & 15, q4 = lane >> 4;
  const int b  = blockIdx.x & 7;                  // batch == XCD
  const int it = blockIdx.x >> 3;
  const int i0 = it * 64;
  const float gamma = gptr[0];

  const f16x8 qfr = *(const f16x8*)(qf + ((size_t)(b * N_) + i0 + w * 16 + l15) * CQK + q4 * 8);

  // block-level K base (cooperative LDS staging)
  const _Float16* kstage = kf + (size_t)b * N_ * CQK;
  // per-lane V base (panel-major): c-row = w*64 (+cb*16) + l15, j-chunk q4*8
  const _Float16* vbase = vf + (size_t)b * (64 * VPANEL)
                             + ((size_t)(w * 64 + l15)) * 64 + q4 * 8;

  f32x4 acc[4][4];   // [cb][ib]: c = w*64+cb*16+q4*4+r, i = ib*16+l15
  const f32x4 zf = {0.f, 0.f, 0.f, 0.f};
  #pragma unroll
  for (int a = 0; a < 4; ++a)
    #pragma unroll
    for (int bb = 0; bb < 4; ++bb) acc[a][bb] = zf;

  float mold = -1e30f, lrun = 0.f;

  // prologue: stage K(0) into buf 0
  #pragma unroll
  for (int s = 0; s < 2; ++s) {
    int idx = s * 256 + t;
    f16x8 v = *(const f16x8*)(kstage + (idx >> 2) * CQK + (idx & 3) * 8);
    *(f16x8*)(Klds + (idx >> 2) * KSTRIDE + (idx & 3) * 8) = v;
  }
  __syncthreads();

  #pragma unroll 1
  for (int k = 0; k < 32; k += 2) {
    ATTN_BODY(k, 0);
    ATTN_BODY(k + 1, 1);
  }

  if (q4 == 0) lrowl[w * 16 + l15] = lrun;
  __syncthreads();
  float linv[4];
  #pragma unroll
  for (int ib = 0; ib < 4; ++ib) linv[ib] = 1.0f / lrowl[ib * 16 + l15];

  // epilogue: residual + yout store + fused BN stats into the PER-BATCH
  // stats copy (stats + b*512): 64 same-address atomics instead of 512.
  float* sb = stats + b * 512;
  #pragma unroll
  for (int cb = 0; cb < 4; ++cb) {
    #pragma unroll
    for (int r = 0; r < 4; ++r) {
      int c = w * 64 + cb * 16 + q4 * 4 + r;
      float s1 = 0.f, s2 = 0.f;
      #pragma unroll
      for (int ib = 0; ib < 4; ++ib) {
        int i = i0 + ib * 16 + l15;
        size_t off = ((size_t)(b * C_) + c) * N_ + i;
        float y = fmaf(gamma, acc[cb][ib][r] * linv[ib], x[off]);
        yout[off] = f2bf_rne(y);
        s1 += y;
        s2 += y * y;
      }
      #pragma unroll
      for (int m = 1; m < 16; m <<= 1) {
        s1 += __shfl_xor(s1, m);
        s2 += __shfl_xor(s2, m);
      }
      if (l15 == 0) {
        atomicAdd(sb + c, s1);
        atomicAdd(sb + 256 + c, s2);
      }
    }
  }
}

// ---------------------------------------------------------------------------
// Kernel 6: BN normalize + ReLU: bf16 yout -> fp32 d_out.
// mean/rstd from the 8 per-batch stats copies.
// ---------------------------------------------------------------------------
__global__ __launch_bounds__(256) void bnapply_kernel(
    const unsigned short* __restrict__ y, float* __restrict__ out,
    const float* __restrict__ stats,
    const float* __restrict__ bnw, const float* __restrict__ bnb)
{
  size_t idx = (size_t)blockIdx.x * 256 + threadIdx.x;   // 1,048,576 threads
  size_t el = idx * 8;
  int c = (int)((el >> 12) & 255);
  float s1 = 0.f, s2 = 0.f;
  #pragma unroll
  for (int bb = 0; bb < 8; ++bb) {
    s1 += stats[bb * 512 + c];
    s2 += stats[bb * 512 + 256 + c];
  }
  float mean = s1 * (1.0f / 32768.0f);
  float var  = fmaf(-mean, mean, s2 * (1.0f / 32768.0f));
  float rstd = rsqrtf(var + 1e-5f);
  float sc = bnw[c] * rstd;
  float sh = fmaf(-mean, sc, bnb[c]);
  uint4 u = *(const uint4*)(y + el);
  unsigned uu[4] = {u.x, u.y, u.z, u.w};
  float4 o0, o1;
  float v[8];
  #pragma unroll
  for (int k = 0; k < 4; ++k) {
    v[2 * k]     = __builtin_bit_cast(float, uu[k] << 16);
    v[2 * k + 1] = __builtin_bit_cast(float, uu[k] & 0xFFFF0000u);
  }
  o0.x = fmaxf(fmaf(v[0], sc, sh), 0.f);
  o0.y = fmaxf(fmaf(v[1], sc, sh), 0.f);
  o0.z = fmaxf(fmaf(v[2], sc, sh), 0.f);
  o0.w = fmaxf(fmaf(v[3], sc, sh), 0.f);
  o1.x = fmaxf(fmaf(v[4], sc, sh), 0.f);
  o1.y = fmaxf(fmaf(v[5], sc, sh), 0.f);
  o1.z = fmaxf(fmaf(v[6], sc, sh), 0.f);
  o1.w = fmaxf(fmaf(v[7], sc, sh), 0.f);
  *(float4*)(out + el) = o0;
  *(float4*)(out + el + 4) = o1;
}

extern "C" void kernel_launch(void* const* d_in, const int* in_sizes, int n_in,
                              void* d_out, int out_size, void* d_ws, size_t ws_size,
                              hipStream_t stream)
{
  const float* x   = (const float*)d_in[0];
  const float* wq  = (const float*)d_in[1];
  const float* bq  = (const float*)d_in[2];
  const float* wk  = (const float*)d_in[3];
  const float* bk  = (const float*)d_in[4];
  const float* wv  = (const float*)d_in[5];
  const float* bv  = (const float*)d_in[6];
  const float* gm  = (const float*)d_in[7];
  const float* bnw = (const float*)d_in[8];
  const float* bnb = (const float*)d_in[9];
  float* out = (float*)d_out;

  // d_out doubles as scratch for v (dead before bnapply writes):
  //   [16.78, 33.55)  v fp16 PANEL-MAJOR [b][64 jt][256 c][64 j]
  _Float16* vfp = (_Float16*)((char*)d_out + (size_t)B_ * C_ * N_ * 2);

  // ws: q 2MB | k 2MB | yout bf16 16.78MB | wf 160KB | stats[8][512]
  char* ws = (char*)d_ws;
  _Float16* qf = (_Float16*)(ws);
  _Float16* kf = (_Float16*)(ws + ((size_t)2 << 20));
  unsigned short* yout = (unsigned short*)(ws + ((size_t)4 << 20));
  _Float16* wf = (_Float16*)(ws + ((size_t)21 << 20));
  float* stats = (float*)(ws + ((size_t)22 << 20));

  hipLaunchKernelGGL(wconv_kernel, dim3(80), dim3(256), 0, stream,
                     wq, wk, wv, wf, stats);
  hipLaunchKernelGGL(proj_fused_kernel, dim3(512), dim3(256), 0, stream,
                     x, wf, bq, bk, bv, qf, kf, vfp);
  hipLaunchKernelGGL(attn_kernel, dim3(512), dim3(256), 0, stream,
                     x, gm, qf, kf, vfp, yout, stats);
  hipLaunchKernelGGL(bnapply_kernel, dim3(4096), dim3(256), 0, stream,
                     yout, out, stats, bnw, bnb);
}